// Round 1
// baseline (680.257 us; speedup 1.0000x reference)
//
#include <hip/hip_runtime.h>
#include <hip/hip_bf16.h>
#include <cstdint>

#define N_NODES 10000
#define N_EDGES 160000

// ---------------- edge preprocessing ----------------

__global__ void deg_kernel(const int* __restrict__ src, const int* __restrict__ dst,
                           const float* __restrict__ ew,
                           float* __restrict__ deg, int* __restrict__ cnt) {
    int e = blockIdx.x * blockDim.x + threadIdx.x;
    if (e >= N_EDGES) return;
    atomicAdd(&deg[src[e]], ew[e]);   // weighted out-degree by src (for norm)
    atomicAdd(&cnt[dst[e]], 1);       // in-degree by dst (for CSR)
}

__global__ void dis_kernel(const float* __restrict__ deg, float* __restrict__ dis) {
    int n = blockIdx.x * blockDim.x + threadIdx.x;
    if (n >= N_NODES) return;
    float d = deg[n];
    dis[n] = d > 0.f ? rsqrtf(d) : 0.f;
}

// exclusive scan of cnt -> rowptr (rowptr[0]=0, rowptr[N]=E), single block
__global__ __launch_bounds__(1024) void scan_kernel(const int* __restrict__ cnt,
                                                    int* __restrict__ rowptr) {
    __shared__ int wsum[16];
    const int t = threadIdx.x, lane = t & 63, wid = t >> 6;
    int carry = 0;
    for (int base = 0; base < N_NODES; base += 1024) {
        int i = base + t;
        int v = (i < N_NODES) ? cnt[i] : 0;
        int s = v;
        #pragma unroll
        for (int off = 1; off < 64; off <<= 1) {
            int u = __shfl_up(s, off);
            if (lane >= off) s += u;
        }
        if (lane == 63) wsum[wid] = s;
        __syncthreads();
        int woff = 0, tot = 0;
        for (int ww = 0; ww < 16; ++ww) {
            int xv = wsum[ww];
            if (ww < wid) woff += xv;
            tot += xv;
        }
        if (i < N_NODES) rowptr[i + 1] = carry + woff + s;
        carry += tot;
        __syncthreads();   // protect wsum before next chunk overwrites
    }
    if (t == 0) rowptr[0] = 0;
}

__global__ void fill_kernel(const int* __restrict__ src, const int* __restrict__ dst,
                            const float* __restrict__ ew, const float* __restrict__ dis,
                            const int* __restrict__ rowptr, int* __restrict__ fill,
                            int* __restrict__ csr_src, float* __restrict__ csr_w) {
    int e = blockIdx.x * blockDim.x + threadIdx.x;
    if (e >= N_EDGES) return;
    int s = src[e], d = dst[e];
    int pos = rowptr[d] + atomicAdd(&fill[d], 1);
    csr_src[pos] = s;
    csr_w[pos] = -dis[s] * ew[e] * dis[d];   // sym-normalized, lambda_max=2 scaled
}

// ---------------- fp32 tiled GEMM: C = A(MxK) @ W(KxNc) [+C if accFlag] ----------------
// BM x BN block tile, 256 threads as 16x16, each thread TM x TN outputs.

template <int BM, int BN, int TM, int TN>
__global__ __launch_bounds__(256) void gemm_kernel(const float* __restrict__ A,
                                                   const float* __restrict__ W,
                                                   float* __restrict__ C,
                                                   int M, int K, int Nc, int accFlag) {
    constexpr int BK = 16;
    __shared__ float As[BK][BM + 4];   // [k][m], padded: conflict-free
    __shared__ float Bs[BK][BN + 4];   // [k][n]
    const int t = threadIdx.x;
    const int tx = t & 15, ty = t >> 4;
    const int row0 = blockIdx.x * BM, col0 = blockIdx.y * BN;

    float acc[TM][TN];
    #pragma unroll
    for (int i = 0; i < TM; ++i)
        #pragma unroll
        for (int j = 0; j < TN; ++j) acc[i][j] = 0.f;

    constexpr int AV = BM * BK / (256 * 4);   // float4 A-loads per thread
    constexpr int BV = BN * BK / (256 * 4);
    constexpr int R4 = BN / 4;                // float4 per B row

    for (int k0 = 0; k0 < K; k0 += BK) {
        #pragma unroll
        for (int l = 0; l < AV; ++l) {
            int idx = t + l * 256;            // 0 .. BM*4-1
            int r = idx >> 2, kq = (idx & 3) << 2;
            int gr = row0 + r;
            float4 a = {0.f, 0.f, 0.f, 0.f};
            if (gr < M) a = *(const float4*)&A[(size_t)gr * K + k0 + kq];
            As[kq + 0][r] = a.x; As[kq + 1][r] = a.y;
            As[kq + 2][r] = a.z; As[kq + 3][r] = a.w;
        }
        #pragma unroll
        for (int l = 0; l < BV; ++l) {
            int idx = t + l * 256;
            int kr = idx / R4, c4 = (idx % R4) * 4;
            *(float4*)&Bs[kr][c4] = *(const float4*)&W[(size_t)(k0 + kr) * Nc + col0 + c4];
        }
        __syncthreads();
        #pragma unroll
        for (int kk = 0; kk < BK; ++kk) {
            float a[TM], b[TN];
            {
                float4 a0 = *(const float4*)&As[kk][ty * TM];
                a[0] = a0.x; a[1] = a0.y; a[2] = a0.z; a[3] = a0.w;
                if constexpr (TM == 8) {
                    float4 a1 = *(const float4*)&As[kk][ty * TM + 4];
                    a[4] = a1.x; a[5] = a1.y; a[6] = a1.z; a[7] = a1.w;
                }
            }
            {
                float4 b0 = *(const float4*)&Bs[kk][tx * 4];
                b[0] = b0.x; b[1] = b0.y; b[2] = b0.z; b[3] = b0.w;
                if constexpr (TN == 8) {   // second chunk at BN/2 (2-way banks, free)
                    float4 b1 = *(const float4*)&Bs[kk][BN / 2 + tx * 4];
                    b[4] = b1.x; b[5] = b1.y; b[6] = b1.z; b[7] = b1.w;
                }
            }
            #pragma unroll
            for (int i = 0; i < TM; ++i)
                #pragma unroll
                for (int j = 0; j < TN; ++j) acc[i][j] += a[i] * b[j];
        }
        __syncthreads();
    }

    #pragma unroll
    for (int i = 0; i < TM; ++i) {
        int r = row0 + ty * TM + i;
        if (r >= M) continue;
        #pragma unroll
        for (int jc = 0; jc < TN / 4; ++jc) {
            size_t base = (size_t)r * Nc + col0 + jc * (BN / 2) + tx * 4;
            float4 v;
            v.x = acc[i][jc * 4 + 0]; v.y = acc[i][jc * 4 + 1];
            v.z = acc[i][jc * 4 + 2]; v.w = acc[i][jc * 4 + 3];
            if (accFlag) {
                float4 c = *(const float4*)&C[base];
                v.x += c.x; v.y += c.y; v.z += c.z; v.w += c.w;
            }
            *(float4*)&C[base] = v;
        }
    }
}

// ---------------- batch norm (training mode, over node dim) ----------------

template <int F>
__global__ __launch_bounds__(256) void bn_stats_kernel(const float* __restrict__ h,
                                                       float* __restrict__ sums, int M) {
    constexpr int CPT = (F + 255) / 256;
    const int t = threadIdx.x;
    float s[CPT], q[CPT];
    #pragma unroll
    for (int i = 0; i < CPT; ++i) { s[i] = 0.f; q[i] = 0.f; }
    int r0 = blockIdx.x * 40;
    int r1 = min(r0 + 40, M);
    for (int r = r0; r < r1; ++r) {
        const float* row = h + (size_t)r * F;
        #pragma unroll
        for (int i = 0; i < CPT; ++i) {
            int c = t + i * 256;
            if (c < F) { float v = row[c]; s[i] += v; q[i] += v * v; }
        }
    }
    #pragma unroll
    for (int i = 0; i < CPT; ++i) {
        int c = t + i * 256;
        if (c < F) { atomicAdd(&sums[c], s[i]); atomicAdd(&sums[F + c], q[i]); }
    }
}

__global__ void bn_coeffs_kernel(const float* __restrict__ sums, const float* __restrict__ g,
                                 const float* __restrict__ be, float* __restrict__ sc,
                                 float* __restrict__ sh, int F) {
    int c = blockIdx.x * blockDim.x + threadIdx.x;
    if (c >= F) return;
    const float invM = 1.0f / (float)N_NODES;
    float mu = sums[c] * invM;
    float var = sums[F + c] * invM - mu * mu;
    float s = g[c] * rsqrtf(var + 1e-5f);
    sc[c] = s;
    sh[c] = be[c] - mu * s;
}

template <bool RELU, int F>
__global__ void bn_apply_kernel(float* __restrict__ h, const float* __restrict__ sc,
                                const float* __restrict__ sh) {
    int i = blockIdx.x * blockDim.x + threadIdx.x;
    int i4 = i * 4;
    if (i4 >= N_NODES * F) return;
    int c = i4 & (F - 1);
    float4 v = *(float4*)&h[i4];
    v.x = v.x * sc[c + 0] + sh[c + 0];
    v.y = v.y * sc[c + 1] + sh[c + 1];
    v.z = v.z * sc[c + 2] + sh[c + 2];
    v.w = v.w * sc[c + 3] + sh[c + 3];
    if (RELU) {
        v.x = fmaxf(v.x, 0.f); v.y = fmaxf(v.y, 0.f);
        v.z = fmaxf(v.z, 0.f); v.w = fmaxf(v.w, 0.f);
    }
    *(float4*)&h[i4] = v;
}

// ---------------- graph propagate: out[n] = alpha*sum_e w_e*h[src_e] + beta*base[n] ----------------
// F = 256 fixed (blockDim), one block per dst node, CSR gather, no atomics.

__global__ __launch_bounds__(256) void prop_kernel(const float* __restrict__ h,
                                                   const float* __restrict__ base,
                                                   const int* __restrict__ rowptr,
                                                   const int* __restrict__ csr_src,
                                                   const float* __restrict__ csr_w,
                                                   float alpha, float beta,
                                                   float* __restrict__ out) {
    constexpr int F = 256;
    const int n = blockIdx.x;
    const int f = threadIdx.x;
    const int e1 = rowptr[n + 1];
    float acc = 0.f;
    int e = rowptr[n];
    for (; e + 1 < e1; e += 2) {
        int s0 = csr_src[e], s1 = csr_src[e + 1];
        float w0 = csr_w[e], w1 = csr_w[e + 1];
        acc += w0 * h[(size_t)s0 * F + f] + w1 * h[(size_t)s1 * F + f];
    }
    if (e < e1) {
        int s0 = csr_src[e];
        acc += csr_w[e] * h[(size_t)s0 * F + f];
    }
    float v = alpha * acc;
    if (beta != 0.f) v += beta * base[(size_t)n * F + f];
    out[(size_t)n * F + f] = v;
}

// ---------------- fused BN3 + FC(128->6) + log_softmax; one wave per row ----------------

__global__ __launch_bounds__(256) void final_kernel(const float* __restrict__ h,
                                                    const float* __restrict__ sc,
                                                    const float* __restrict__ sh,
                                                    const float* __restrict__ fcW,
                                                    const float* __restrict__ fcb,
                                                    float* __restrict__ out) {
    const int t = threadIdx.x, lane = t & 63, wid = t >> 6;
    const int r = blockIdx.x * 4 + wid;
    if (r >= N_NODES) return;
    float v[6] = {0.f, 0.f, 0.f, 0.f, 0.f, 0.f};
    #pragma unroll
    for (int kk = 0; kk < 2; ++kk) {
        int k = lane + kk * 64;
        float x = h[(size_t)r * 128 + k] * sc[k] + sh[k];
        #pragma unroll
        for (int j = 0; j < 6; ++j) v[j] += x * fcW[k * 6 + j];
    }
    #pragma unroll
    for (int j = 0; j < 6; ++j)
        #pragma unroll
        for (int off = 32; off > 0; off >>= 1) v[j] += __shfl_down(v[j], off);
    if (lane == 0) {
        #pragma unroll
        for (int j = 0; j < 6; ++j) v[j] += fcb[j];
        float m = v[0];
        #pragma unroll
        for (int j = 1; j < 6; ++j) m = fmaxf(m, v[j]);
        float s = 0.f;
        #pragma unroll
        for (int j = 0; j < 6; ++j) s += expf(v[j] - m);
        float l = m + logf(s);
        #pragma unroll
        for (int j = 0; j < 6; ++j) out[r * 6 + j] = v[j] - l;
    }
}

// ---------------- launch ----------------

extern "C" void kernel_launch(void* const* d_in, const int* in_sizes, int n_in,
                              void* d_out, int out_size, void* d_ws, size_t ws_size,
                              hipStream_t stream) {
    (void)in_sizes; (void)n_in; (void)out_size; (void)ws_size;
    const float* x   = (const float*)d_in[0];
    const int*   ei  = (const int*)d_in[1];
    const float* ea  = (const float*)d_in[2];
    const float* W1  = (const float*)d_in[3];
    // d_in[4] = b1 : cancels under training-mode BN (mean/var translation invariant)
    const float* g1  = (const float*)d_in[5];
    const float* be1 = (const float*)d_in[6];
    const float* W2a = (const float*)d_in[7];
    const float* W2b = (const float*)d_in[8];
    // d_in[9] = b2 : cancels
    const float* g2  = (const float*)d_in[10];
    const float* be2 = (const float*)d_in[11];
    const float* W3a = (const float*)d_in[12];
    const float* W3b = (const float*)d_in[13];
    const float* W3c = (const float*)d_in[14];
    // d_in[15] = b3 : cancels
    const float* g3  = (const float*)d_in[16];
    const float* be3 = (const float*)d_in[17];
    const float* fcW = (const float*)d_in[18];
    const float* fcb = (const float*)d_in[19];
    float* out = (float*)d_out;

    const int* src = ei;
    const int* dst = ei + N_EDGES;

    // workspace layout (4 KiB-aligned chunks); zeroed region first
    char* w = (char*)d_ws;
    size_t off = 0;
    auto alloc = [&](size_t bytes) -> void* {
        void* p = w + off;
        off += (bytes + 4095) & ~(size_t)4095;
        return p;
    };
    float* deg    = (float*)alloc(N_NODES * 4);        // zeroed
    int*   cnt    = (int*)  alloc(N_NODES * 4);        // zeroed
    int*   fillc  = (int*)  alloc(N_NODES * 4);        // zeroed
    float* sums1  = (float*)alloc(1024 * 4);           // zeroed
    float* sums2  = (float*)alloc(1024 * 4);           // zeroed
    float* sums3  = (float*)alloc(1024 * 4);           // zeroed
    size_t zero_bytes = off;
    float* dis    = (float*)alloc(N_NODES * 4);
    int*   rowptr = (int*)  alloc((N_NODES + 1) * 4);
    int*   csr_s  = (int*)  alloc(N_EDGES * 4);
    float* csr_w  = (float*)alloc(N_EDGES * 4);
    float* sc1 = (float*)alloc(512 * 4);  float* sh1 = (float*)alloc(512 * 4);
    float* sc2 = (float*)alloc(256 * 4);  float* sh2 = (float*)alloc(256 * 4);
    float* sc3 = (float*)alloc(128 * 4);  float* sh3 = (float*)alloc(128 * 4);
    float* bufA = (float*)alloc((size_t)N_NODES * 512 * 4);   // conv1 out / h1
    float* bufB = (float*)alloc((size_t)N_NODES * 256 * 4);   // y1 / Tx2
    float* bufC = (float*)alloc((size_t)N_NODES * 256 * 4);   // y0 / out2 / h2
    float* bufD = (float*)alloc((size_t)N_NODES * 256 * 4);   // Tx1
    float* bufF = (float*)alloc((size_t)N_NODES * 128 * 4);   // conv3 out

    hipMemsetAsync(d_ws, 0, zero_bytes, stream);

    // graph preprocessing -> dst-CSR with normalized weights
    deg_kernel<<<N_EDGES / 256, 256, 0, stream>>>(src, dst, ea, deg, cnt);
    dis_kernel<<<(N_NODES + 255) / 256, 256, 0, stream>>>(deg, dis);
    scan_kernel<<<1, 1024, 0, stream>>>(cnt, rowptr);
    fill_kernel<<<N_EDGES / 256, 256, 0, stream>>>(src, dst, ea, dis, rowptr, fillc,
                                                   csr_s, csr_w);

    // ---- layer 1: h1 = relu(BN(x @ W1)) ----
    gemm_kernel<128, 128, 8, 8><<<dim3(79, 4), 256, 0, stream>>>(x, W1, bufA,
                                                                 N_NODES, 768, 512, 0);
    bn_stats_kernel<512><<<250, 256, 0, stream>>>(bufA, sums1, N_NODES);
    bn_coeffs_kernel<<<2, 256, 0, stream>>>(sums1, g1, be1, sc1, sh1, 512);
    bn_apply_kernel<true, 512><<<(N_NODES * 512 / 4 + 255) / 256, 256, 0, stream>>>(
        bufA, sc1, sh1);

    // ---- layer 2: out2 = h1@W2_0 + prop(h1@W2_1)   (prop pushed past the GEMM) ----
    gemm_kernel<128, 128, 8, 8><<<dim3(79, 2), 256, 0, stream>>>(bufA, W2a, bufC,
                                                                 N_NODES, 512, 256, 0);
    gemm_kernel<128, 128, 8, 8><<<dim3(79, 2), 256, 0, stream>>>(bufA, W2b, bufB,
                                                                 N_NODES, 512, 256, 0);
    prop_kernel<<<N_NODES, 256, 0, stream>>>(bufB, bufC, rowptr, csr_s, csr_w,
                                             1.f, 1.f, bufC);
    bn_stats_kernel<256><<<250, 256, 0, stream>>>(bufC, sums2, N_NODES);
    bn_coeffs_kernel<<<1, 256, 0, stream>>>(sums2, g2, be2, sc2, sh2, 256);
    bn_apply_kernel<true, 256><<<(N_NODES * 256 / 4 + 255) / 256, 256, 0, stream>>>(
        bufC, sc2, sh2);

    // ---- layer 3: Tx1 = prop(h2); Tx2 = 2*prop(Tx1) - h2 ----
    prop_kernel<<<N_NODES, 256, 0, stream>>>(bufC, nullptr, rowptr, csr_s, csr_w,
                                             1.f, 0.f, bufD);
    prop_kernel<<<N_NODES, 256, 0, stream>>>(bufD, bufC, rowptr, csr_s, csr_w,
                                             2.f, -1.f, bufB);
    gemm_kernel<64, 64, 4, 4><<<dim3(157, 2), 256, 0, stream>>>(bufC, W3a, bufF,
                                                                N_NODES, 256, 128, 0);
    gemm_kernel<64, 64, 4, 4><<<dim3(157, 2), 256, 0, stream>>>(bufD, W3b, bufF,
                                                                N_NODES, 256, 128, 1);
    gemm_kernel<64, 64, 4, 4><<<dim3(157, 2), 256, 0, stream>>>(bufB, W3c, bufF,
                                                                N_NODES, 256, 128, 1);
    bn_stats_kernel<128><<<250, 256, 0, stream>>>(bufF, sums3, N_NODES);
    bn_coeffs_kernel<<<1, 128, 0, stream>>>(sums3, g3, be3, sc3, sh3, 128);

    // ---- BN3 + FC + log_softmax fused ----
    final_kernel<<<2500, 256, 0, stream>>>(bufF, sc3, sh3, fcW, fcb, out);
}

// Round 2
// 464.950 us; speedup vs baseline: 1.4631x; 1.4631x over previous
//
#include <hip/hip_runtime.h>
#include <hip/hip_bf16.h>
#include <cstdint>

#define N_NODES 10000
#define N_EDGES 160000
#define MPAD    10112   // 79 * 128

typedef __attribute__((ext_vector_type(8))) short short8;
typedef __attribute__((ext_vector_type(4))) float floatx4;

// ---------------- helpers ----------------

__device__ __forceinline__ unsigned short bf16_rn(float f) {
    union { float f; unsigned u; } c{f};
    unsigned r = c.u + 0x7FFF + ((c.u >> 16) & 1);   // round-to-nearest-even
    return (unsigned short)(r >> 16);
}
__device__ __forceinline__ float bf16_to_f(unsigned short h) {
    union { unsigned u; float f; } c{(unsigned)h << 16};
    return c.f;
}
// pack2: [lo16 = bf16(a), hi16 = bf16(b)]
__device__ __forceinline__ unsigned pack_hi2(float a, float b) {
    return (unsigned)bf16_rn(a) | ((unsigned)bf16_rn(b) << 16);
}
__device__ __forceinline__ unsigned pack_lo2(float a, float b) {
    float ra = a - bf16_to_f(bf16_rn(a));
    float rb = b - bf16_to_f(bf16_rn(b));
    return (unsigned)bf16_rn(ra) | ((unsigned)bf16_rn(rb) << 16);
}

__device__ __forceinline__ void gload_lds16(const void* g, void* l) {
    __builtin_amdgcn_global_load_lds(
        (const __attribute__((address_space(1))) unsigned int*)g,
        (__attribute__((address_space(3))) unsigned int*)l, 16, 0, 0);
}

// ---------------- edge preprocessing (round-1, proven) ----------------

__global__ void deg_kernel(const int* __restrict__ src, const int* __restrict__ dst,
                           const float* __restrict__ ew,
                           float* __restrict__ deg, int* __restrict__ cnt) {
    int e = blockIdx.x * blockDim.x + threadIdx.x;
    if (e >= N_EDGES) return;
    atomicAdd(&deg[src[e]], ew[e]);
    atomicAdd(&cnt[dst[e]], 1);
}

__global__ void dis_kernel(const float* __restrict__ deg, float* __restrict__ dis) {
    int n = blockIdx.x * blockDim.x + threadIdx.x;
    if (n >= N_NODES) return;
    float d = deg[n];
    dis[n] = d > 0.f ? rsqrtf(d) : 0.f;
}

__global__ __launch_bounds__(1024) void scan_kernel(const int* __restrict__ cnt,
                                                    int* __restrict__ rowptr) {
    __shared__ int wsum[16];
    const int t = threadIdx.x, lane = t & 63, wid = t >> 6;
    int carry = 0;
    for (int base = 0; base < N_NODES; base += 1024) {
        int i = base + t;
        int v = (i < N_NODES) ? cnt[i] : 0;
        int s = v;
        #pragma unroll
        for (int off = 1; off < 64; off <<= 1) {
            int u = __shfl_up(s, off);
            if (lane >= off) s += u;
        }
        if (lane == 63) wsum[wid] = s;
        __syncthreads();
        int woff = 0, tot = 0;
        for (int ww = 0; ww < 16; ++ww) {
            int xv = wsum[ww];
            if (ww < wid) woff += xv;
            tot += xv;
        }
        if (i < N_NODES) rowptr[i + 1] = carry + woff + s;
        carry += tot;
        __syncthreads();
    }
    if (t == 0) rowptr[0] = 0;
}

__global__ void fill_kernel(const int* __restrict__ src, const int* __restrict__ dst,
                            const float* __restrict__ ew, const float* __restrict__ dis,
                            const int* __restrict__ rowptr, int* __restrict__ fill,
                            int* __restrict__ csr_src, float* __restrict__ csr_w) {
    int e = blockIdx.x * blockDim.x + threadIdx.x;
    if (e >= N_EDGES) return;
    int s = src[e], d = dst[e];
    int pos = rowptr[d] + atomicAdd(&fill[d], 1);
    csr_src[pos] = s;
    csr_w[pos] = -dis[s] * ew[e] * dis[d];
}

// ---------------- fp32 -> bf16 hi/lo conversions ----------------
// A' layout: [Mpad][2K] bf16, cols [0,K)=hi, [K,2K)=lo
// GEMM iterates K'=3K with block map A:[hi,lo,hi], B:[hi,hi,lo]

__global__ __launch_bounds__(256) void cvt_x_kernel(const float* __restrict__ x,
                                                    unsigned short* __restrict__ Ap,
                                                    int M, int K) {
    int i = blockIdx.x * 256 + threadIdx.x;      // float4 index
    int kq4 = K >> 2;
    if (i >= M * kq4) return;
    int m = i / kq4, kq = i - m * kq4;
    float4 v = ((const float4*)x)[i];
    uint2 hi, lo;
    hi.x = pack_hi2(v.x, v.y); hi.y = pack_hi2(v.z, v.w);
    lo.x = pack_lo2(v.x, v.y); lo.y = pack_lo2(v.z, v.w);
    size_t row = (size_t)m * 2 * K;
    *(uint2*)&Ap[row + kq * 4]     = hi;
    *(uint2*)&Ap[row + K + kq * 4] = lo;
}

// fused: v = relu(G*sc + sh) then split hi/lo
__global__ __launch_bounds__(256) void bn_relu_cvt_kernel(const float* __restrict__ G,
                                                          const float* __restrict__ sc,
                                                          const float* __restrict__ sh,
                                                          unsigned short* __restrict__ Ap,
                                                          int M, int F) {
    int i = blockIdx.x * 256 + threadIdx.x;
    int fq4 = F >> 2;
    if (i >= M * fq4) return;
    int m = i / fq4, kq = i - m * fq4;
    float4 v = ((const float4*)G)[i];
    float4 s = ((const float4*)sc)[kq];
    float4 b = ((const float4*)sh)[kq];
    v.x = fmaxf(v.x * s.x + b.x, 0.f);
    v.y = fmaxf(v.y * s.y + b.y, 0.f);
    v.z = fmaxf(v.z * s.z + b.z, 0.f);
    v.w = fmaxf(v.w * s.w + b.w, 0.f);
    uint2 hi, lo;
    hi.x = pack_hi2(v.x, v.y); hi.y = pack_hi2(v.z, v.w);
    lo.x = pack_lo2(v.x, v.y); lo.y = pack_lo2(v.z, v.w);
    size_t row = (size_t)m * 2 * F;
    *(uint2*)&Ap[row + kq * 4]     = hi;
    *(uint2*)&Ap[row + F + kq * 4] = lo;
}

// W (KxN fp32 row-major) -> BpT (N x 2K bf16): [n][k]=hi, [n][K+k]=lo
__global__ __launch_bounds__(256) void cvt_w_kernel(const float* __restrict__ W,
                                                    unsigned short* __restrict__ BpT,
                                                    int K, int N) {
    int i = blockIdx.x * 256 + threadIdx.x;
    if (i >= N * (K >> 3)) return;
    int n = i % N, k8 = i / N;
    float v[8];
    #pragma unroll
    for (int j = 0; j < 8; ++j) v[j] = W[(size_t)(k8 * 8 + j) * N + n];
    uint4 hi, lo;
    hi.x = pack_hi2(v[0], v[1]); hi.y = pack_hi2(v[2], v[3]);
    hi.z = pack_hi2(v[4], v[5]); hi.w = pack_hi2(v[6], v[7]);
    lo.x = pack_lo2(v[0], v[1]); lo.y = pack_lo2(v[2], v[3]);
    lo.z = pack_lo2(v[4], v[5]); lo.w = pack_lo2(v[6], v[7]);
    size_t row = (size_t)n * 2 * K;
    *(uint4*)&BpT[row + k8 * 8]     = hi;
    *(uint4*)&BpT[row + K + k8 * 8] = lo;
}

// ---------------- bf16x3 MFMA GEMM (m97 structure: 128x128 tile, BK=32) ----------------
// C(MxNc) = A(Mx3K') * B(3K'xNc) with A',B' stored compact [hi|lo] (width 2*Ksub)

__global__ __launch_bounds__(256, 2) void mfma_gemm_kernel(
        const unsigned short* __restrict__ Ap,    // Mpad x 2*Ksub
        const unsigned short* __restrict__ BpT,   // Nc x 2*Ksub
        float* __restrict__ C,                    // M x Nc
        int M, int Ksub, int Nc, int ncb) {
    constexpr int BK = 32;
    __shared__ unsigned short As[128 * BK];
    __shared__ unsigned short Bs[128 * BK];
    const int t = threadIdx.x;
    const int w = t >> 6, l = t & 63;

    // bijective XCD swizzle (m204): contiguous wgid chunk per XCD
    int nwg = gridDim.x, bid = blockIdx.x;
    int q = nwg >> 3, r = nwg & 7;
    int xcd = bid & 7, idx = bid >> 3;
    int wgid = (xcd < r ? xcd * (q + 1) : r * (q + 1) + (xcd - r) * q) + idx;
    const int row0 = (wgid / ncb) * 128;
    const int col0 = (wgid % ncb) * 128;

    const int lda = 2 * Ksub;
    const int Ktot = 3 * Ksub;
    const int wr = w >> 1, wc = w & 1;      // 2x2 waves, 64x64 wave tile
    const int lr = l & 15, kq = l >> 4;

    // staging coords: unit u covers 16 rows (1 KiB); lane l -> row u*16+l/4, 16B chunk l%4
    const int srow = l >> 2;
    const int skc  = l & 3;

    floatx4 acc[4][4] = {};

    for (int k0 = 0; k0 < Ktot; k0 += BK) {
        int kA = (k0 < 2 * Ksub) ? k0 : k0 - 2 * Ksub;   // A blocks: hi, lo, hi
        int kB = (k0 < Ksub)     ? k0 : k0 - Ksub;       // B blocks: hi, hi, lo
        #pragma unroll
        for (int i = 0; i < 2; ++i) {
            int u = i * 4 + w;
            int row = u * 16 + srow;
            gload_lds16(Ap + (size_t)(row0 + row) * lda + kA + skc * 8,
                        (char*)As + u * 1024);
            gload_lds16(BpT + (size_t)(col0 + row) * lda + kB + skc * 8,
                        (char*)Bs + u * 1024);
        }
        __syncthreads();
        short8 af[4], bfr[4];
        #pragma unroll
        for (int m = 0; m < 4; ++m)
            af[m] = *(const short8*)&As[(wr * 64 + m * 16 + lr) * BK + kq * 8];
        #pragma unroll
        for (int n = 0; n < 4; ++n)
            bfr[n] = *(const short8*)&Bs[(wc * 64 + n * 16 + lr) * BK + kq * 8];
        #pragma unroll
        for (int m = 0; m < 4; ++m)
            #pragma unroll
            for (int n = 0; n < 4; ++n)
                acc[m][n] = __builtin_amdgcn_mfma_f32_16x16x32_bf16(
                    af[m], bfr[n], acc[m][n], 0, 0, 0);
        __syncthreads();
    }

    // epilogue: C/D layout col=lane&15, row=(lane>>4)*4+j  [m89/m91]
    #pragma unroll
    for (int m = 0; m < 4; ++m) {
        int rb = row0 + wr * 64 + m * 16 + kq * 4;
        #pragma unroll
        for (int j = 0; j < 4; ++j) {
            int rr = rb + j;
            if (rr < M) {
                #pragma unroll
                for (int n = 0; n < 4; ++n)
                    C[(size_t)rr * Nc + col0 + wc * 64 + n * 16 + lr] = acc[m][n][j];
            }
        }
    }
}

// ---------------- batch-norm stats / coeffs ----------------

template <int F>
__global__ __launch_bounds__(256) void bn_stats_kernel(const float* __restrict__ h,
                                                       float* __restrict__ sums, int M) {
    constexpr int CPT = (F + 255) / 256;
    const int t = threadIdx.x;
    float s[CPT], qv[CPT];
    #pragma unroll
    for (int i = 0; i < CPT; ++i) { s[i] = 0.f; qv[i] = 0.f; }
    int r0 = blockIdx.x * 40;
    int r1 = min(r0 + 40, M);
    for (int r = r0; r < r1; ++r) {
        const float* row = h + (size_t)r * F;
        #pragma unroll
        for (int i = 0; i < CPT; ++i) {
            int c = t + i * 256;
            if (c < F) { float v = row[c]; s[i] += v; qv[i] += v * v; }
        }
    }
    #pragma unroll
    for (int i = 0; i < CPT; ++i) {
        int c = t + i * 256;
        if (c < F) { atomicAdd(&sums[c], s[i]); atomicAdd(&sums[F + c], qv[i]); }
    }
}

__global__ void bn_coeffs_kernel(const float* __restrict__ sums, const float* __restrict__ g,
                                 const float* __restrict__ be, float* __restrict__ sc,
                                 float* __restrict__ sh, int F) {
    int c = blockIdx.x * blockDim.x + threadIdx.x;
    if (c >= F) return;
    const float invM = 1.0f / (float)N_NODES;
    float mu = sums[c] * invM;
    float var = sums[F + c] * invM - mu * mu;
    float s = g[c] * rsqrtf(var + 1e-5f);
    sc[c] = s;
    sh[c] = be[c] - mu * s;
}

// ---------------- graph propagation ----------------

// out2[n][f] = G2[n][f] + sum_e w * G2[src][256+f]   (f in [0,256))
__global__ __launch_bounds__(256) void prop_l2_kernel(const float* __restrict__ G2,
                                                      const int* __restrict__ rowptr,
                                                      const int* __restrict__ csr_s,
                                                      const float* __restrict__ csr_w,
                                                      float* __restrict__ out2) {
    const int n = blockIdx.x, f = threadIdx.x;
    const int e1 = rowptr[n + 1];
    float acc = 0.f;
    int e = rowptr[n];
    for (; e + 1 < e1; e += 2) {
        int s0 = csr_s[e], s1 = csr_s[e + 1];
        float w0 = csr_w[e], w1 = csr_w[e + 1];
        acc += w0 * G2[(size_t)s0 * 512 + 256 + f] + w1 * G2[(size_t)s1 * 512 + 256 + f];
    }
    if (e < e1) acc += csr_w[e] * G2[(size_t)csr_s[e] * 512 + 256 + f];
    out2[(size_t)n * 256 + f] = acc + G2[(size_t)n * 512 + f];
}

// F=128 prop, 2 nodes/block: out[n][f] = sum_e w*(H[src*ldH+offH+f] + s2*H2[src*128+f])
__global__ __launch_bounds__(256) void prop_f128_kernel(const float* __restrict__ H,
                                                        int ldH, int offH,
                                                        const float* __restrict__ H2,
                                                        float s2,
                                                        const int* __restrict__ rowptr,
                                                        const int* __restrict__ csr_s,
                                                        const float* __restrict__ csr_w,
                                                        float* __restrict__ out) {
    const int n = blockIdx.x * 2 + (threadIdx.x >> 7);
    const int f = threadIdx.x & 127;
    const int e1 = rowptr[n + 1];
    float acc = 0.f;
    if (H2) {
        for (int e = rowptr[n]; e < e1; ++e) {
            int s = csr_s[e];
            acc += csr_w[e] * (H[(size_t)s * ldH + offH + f] + s2 * H2[(size_t)s * 128 + f]);
        }
    } else {
        int e = rowptr[n];
        for (; e + 1 < e1; e += 2) {
            int s0 = csr_s[e], s1 = csr_s[e + 1];
            acc += csr_w[e] * H[(size_t)s0 * ldH + offH + f]
                 + csr_w[e + 1] * H[(size_t)s1 * ldH + offH + f];
        }
        if (e < e1) acc += csr_w[e] * H[(size_t)csr_s[e] * ldH + offH + f];
    }
    out[(size_t)n * 128 + f] = acc;
}

// out3 = G3[:,0:128] - G3[:,256:384] + U ; write F and accumulate BN stats
__global__ __launch_bounds__(128) void combine3_stats_kernel(const float* __restrict__ G3,
                                                             const float* __restrict__ U,
                                                             float* __restrict__ Fbuf,
                                                             float* __restrict__ sums) {
    const int t = threadIdx.x;
    int r0 = blockIdx.x * 80, r1 = min(r0 + 80, N_NODES);
    float s = 0.f, q = 0.f;
    for (int r = r0; r < r1; ++r) {
        float v = G3[(size_t)r * 384 + t] - G3[(size_t)r * 384 + 256 + t]
                + U[(size_t)r * 128 + t];
        Fbuf[(size_t)r * 128 + t] = v;
        s += v; q += v * v;
    }
    atomicAdd(&sums[t], s);
    atomicAdd(&sums[128 + t], q);
}

// ---------------- fused BN3 + FC(128->6) + log_softmax ----------------

__global__ __launch_bounds__(256) void final_kernel(const float* __restrict__ h,
                                                    const float* __restrict__ sc,
                                                    const float* __restrict__ sh,
                                                    const float* __restrict__ fcW,
                                                    const float* __restrict__ fcb,
                                                    float* __restrict__ out) {
    const int t = threadIdx.x, lane = t & 63, wid = t >> 6;
    const int r = blockIdx.x * 4 + wid;
    if (r >= N_NODES) return;
    float v[6] = {0.f, 0.f, 0.f, 0.f, 0.f, 0.f};
    #pragma unroll
    for (int kk = 0; kk < 2; ++kk) {
        int k = lane + kk * 64;
        float x = h[(size_t)r * 128 + k] * sc[k] + sh[k];
        #pragma unroll
        for (int j = 0; j < 6; ++j) v[j] += x * fcW[k * 6 + j];
    }
    #pragma unroll
    for (int j = 0; j < 6; ++j)
        #pragma unroll
        for (int off = 32; off > 0; off >>= 1) v[j] += __shfl_down(v[j], off);
    if (lane == 0) {
        #pragma unroll
        for (int j = 0; j < 6; ++j) v[j] += fcb[j];
        float m = v[0];
        #pragma unroll
        for (int j = 1; j < 6; ++j) m = fmaxf(m, v[j]);
        float s = 0.f;
        #pragma unroll
        for (int j = 0; j < 6; ++j) s += expf(v[j] - m);
        float l = m + logf(s);
        #pragma unroll
        for (int j = 0; j < 6; ++j) out[r * 6 + j] = v[j] - l;
    }
}

// ---------------- launch ----------------

extern "C" void kernel_launch(void* const* d_in, const int* in_sizes, int n_in,
                              void* d_out, int out_size, void* d_ws, size_t ws_size,
                              hipStream_t stream) {
    (void)in_sizes; (void)n_in; (void)out_size; (void)ws_size;
    const float* x   = (const float*)d_in[0];
    const int*   ei  = (const int*)d_in[1];
    const float* ea  = (const float*)d_in[2];
    const float* W1  = (const float*)d_in[3];
    // b1/b2/b3 (d_in[4],[9],[15]) cancel under training-mode BN
    const float* g1  = (const float*)d_in[5];
    const float* be1 = (const float*)d_in[6];
    const float* W2a = (const float*)d_in[7];
    const float* W2b = (const float*)d_in[8];
    const float* g2  = (const float*)d_in[10];
    const float* be2 = (const float*)d_in[11];
    const float* W3a = (const float*)d_in[12];
    const float* W3b = (const float*)d_in[13];
    const float* W3c = (const float*)d_in[14];
    const float* g3  = (const float*)d_in[16];
    const float* be3 = (const float*)d_in[17];
    const float* fcW = (const float*)d_in[18];
    const float* fcb = (const float*)d_in[19];
    float* out = (float*)d_out;

    const int* src = ei;
    const int* dst = ei + N_EDGES;

    char* w = (char*)d_ws;
    size_t off = 0;
    auto alloc = [&](size_t bytes) -> void* {
        void* p = w + off;
        off += (bytes + 4095) & ~(size_t)4095;
        return p;
    };
    // zeroed region first
    float* deg    = (float*)alloc(N_NODES * 4);
    int*   cnt    = (int*)  alloc(N_NODES * 4);
    int*   fillc  = (int*)  alloc(N_NODES * 4);
    float* sums1  = (float*)alloc(1024 * 4);
    float* sums2  = (float*)alloc(1024 * 4);
    float* sums3  = (float*)alloc(1024 * 4);
    size_t zero_bytes = off;
    float* dis    = (float*)alloc(N_NODES * 4);
    int*   rowptr = (int*)  alloc((N_NODES + 1) * 4);
    int*   csr_s  = (int*)  alloc(N_EDGES * 4);
    float* csr_w  = (float*)alloc(N_EDGES * 4);
    float* sc1 = (float*)alloc(512 * 4);  float* sh1 = (float*)alloc(512 * 4);
    float* sc2 = (float*)alloc(256 * 4);  float* sh2 = (float*)alloc(256 * 4);
    float* sc3 = (float*)alloc(128 * 4);  float* sh3 = (float*)alloc(128 * 4);
    unsigned short* B1T = (unsigned short*)alloc((size_t)512 * 1536 * 2);
    unsigned short* B2T = (unsigned short*)alloc((size_t)512 * 1024 * 2);
    unsigned short* B3T = (unsigned short*)alloc((size_t)384 * 512 * 2);
    // aliased big slots
    unsigned short* slotA = (unsigned short*)alloc((size_t)MPAD * 1536 * 2); // A'1/A'2/A'3
    float* slotG = (float*)alloc((size_t)N_NODES * 512 * 4);                 // G1/G2/G3
    float* slotC = (float*)alloc((size_t)N_NODES * 256 * 4);                 // out2 ; then T|U
    float* bufF  = (float*)alloc((size_t)N_NODES * 128 * 4);

    unsigned short* A1 = slotA;        // MPAD x 1536
    unsigned short* A2 = slotA;        // MPAD x 1024
    unsigned short* A3 = slotA;        // MPAD x 512
    float* G1 = slotG;                 // M x 512
    float* G2 = slotG;                 // M x 512
    float* G3 = slotG;                 // M x 384
    float* out2 = slotC;               // M x 256
    float* bufT = slotC;                          // M x 128
    float* bufU = slotC + (size_t)N_NODES * 128;  // M x 128

    hipMemsetAsync(d_ws, 0, zero_bytes, stream);

    // graph preprocessing -> dst-CSR with normalized weights
    deg_kernel<<<N_EDGES / 256, 256, 0, stream>>>(src, dst, ea, deg, cnt);
    dis_kernel<<<(N_NODES + 255) / 256, 256, 0, stream>>>(deg, dis);
    scan_kernel<<<1, 1024, 0, stream>>>(cnt, rowptr);
    fill_kernel<<<N_EDGES / 256, 256, 0, stream>>>(src, dst, ea, dis, rowptr, fillc,
                                                   csr_s, csr_w);

    // weight conversions (hi/lo bf16, transposed)
    cvt_w_kernel<<<192, 256, 0, stream>>>(W1, B1T, 768, 512);
    cvt_w_kernel<<<64, 256, 0, stream>>>(W2a, B2T, 512, 256);
    cvt_w_kernel<<<64, 256, 0, stream>>>(W2b, B2T + (size_t)256 * 1024, 512, 256);
    cvt_w_kernel<<<16, 256, 0, stream>>>(W3a, B3T, 256, 128);
    cvt_w_kernel<<<16, 256, 0, stream>>>(W3b, B3T + (size_t)128 * 512, 256, 128);
    cvt_w_kernel<<<16, 256, 0, stream>>>(W3c, B3T + (size_t)256 * 512, 256, 128);

    // ---- layer 1: G1 = x @ W1 (bf16x3), stats, fused BN+ReLU+cvt -> A'2 ----
    cvt_x_kernel<<<7500, 256, 0, stream>>>(x, A1, N_NODES, 768);
    mfma_gemm_kernel<<<316, 256, 0, stream>>>(A1, B1T, G1, N_NODES, 768, 512, 4);
    bn_stats_kernel<512><<<250, 256, 0, stream>>>(G1, sums1, N_NODES);
    bn_coeffs_kernel<<<2, 256, 0, stream>>>(sums1, g1, be1, sc1, sh1, 512);
    bn_relu_cvt_kernel<<<5000, 256, 0, stream>>>(G1, sc1, sh1, A2, N_NODES, 512);

    // ---- layer 2: G2 = h1 @ [W2a|W2b]; out2 = y0 + P y1; stats; cvt -> A'3 ----
    mfma_gemm_kernel<<<316, 256, 0, stream>>>(A2, B2T, G2, N_NODES, 512, 512, 4);
    prop_l2_kernel<<<N_NODES, 256, 0, stream>>>(G2, rowptr, csr_s, csr_w, out2);
    bn_stats_kernel<256><<<250, 256, 0, stream>>>(out2, sums2, N_NODES);
    bn_coeffs_kernel<<<1, 256, 0, stream>>>(sums2, g2, be2, sc2, sh2, 256);
    bn_relu_cvt_kernel<<<2500, 256, 0, stream>>>(out2, sc2, sh2, A3, N_NODES, 256);

    // ---- layer 3: G3 = h2 @ [W3a|W3b|W3c] = [f0|g1|g2] ----
    mfma_gemm_kernel<<<237, 256, 0, stream>>>(A3, B3T, G3, N_NODES, 256, 384, 3);
    // t = P g2 ; u = P (g1 + 2 t) ; out3 = f0 - g2 + u
    prop_f128_kernel<<<N_NODES / 2, 256, 0, stream>>>(G3, 384, 256, nullptr, 0.f,
                                                      rowptr, csr_s, csr_w, bufT);
    prop_f128_kernel<<<N_NODES / 2, 256, 0, stream>>>(G3, 384, 128, bufT, 2.f,
                                                      rowptr, csr_s, csr_w, bufU);
    combine3_stats_kernel<<<125, 128, 0, stream>>>(G3, bufU, bufF, sums3);
    bn_coeffs_kernel<<<1, 128, 0, stream>>>(sums3, g3, be3, sc3, sh3, 128);

    // ---- BN3 + FC + log_softmax fused ----
    final_kernel<<<2500, 256, 0, stream>>>(bufF, sc3, sh3, fcW, fcb, out);
}